// Round 2
// baseline (114.361 us; speedup 1.0000x reference)
//
#include <hip/hip_runtime.h>

// ---- problem constants ----
#define HID   1024
#define NEXP  8
#define NPAIR 4096                       // TOKENS * TOPK
#define BMPAD 128                        // segment padding = BM
#define PERM_MAX (NPAIR + NEXP * BMPAD)  // 5120
#define MT_MAX (PERM_MAX / 128)          // 40 M-tiles

typedef unsigned short u16;
typedef __attribute__((ext_vector_type(8))) short bf16x8;
typedef __attribute__((ext_vector_type(4))) float f32x4;
typedef __attribute__((ext_vector_type(4))) unsigned short us4;

static __device__ __forceinline__ u16 f2bf(float f) {
  union { float f; unsigned u; } v; v.f = f;
  unsigned u = v.u;
  unsigned r = (u + 0x7fffu + ((u >> 16) & 1u)) >> 16;
  return (u16)r;
}

static __device__ __forceinline__ void gload16(const void* g, void* l) {
  __builtin_amdgcn_global_load_lds(
      (const __attribute__((address_space(1))) unsigned int*)g,
      (__attribute__((address_space(3))) unsigned int*)l, 16, 0, 0);
}

static __device__ __forceinline__ f32x4 mfma_bf16(bf16x8 a, bf16x8 b, f32x4 c) {
  return __builtin_amdgcn_mfma_f32_16x16x32_bf16(a, b, c, 0, 0, 0);
}

// ---- prep: zero d_out, convert x -> bf16 ----
__global__ __launch_bounds__(256) void k_prep(const float* __restrict__ x,
                                              u16* __restrict__ xb,
                                              float* __restrict__ out) {
  int i = blockIdx.x * 256 + threadIdx.x;   // 1024 blocks * 256 thr * 8 elems = 2M
  int base = i * 8;
  f32x4 v0 = *(const f32x4*)(x + base);
  f32x4 v1 = *(const f32x4*)(x + base + 4);
  us4 a = { f2bf(v0[0]), f2bf(v0[1]), f2bf(v0[2]), f2bf(v0[3]) };
  us4 b = { f2bf(v1[0]), f2bf(v1[1]), f2bf(v1[2]), f2bf(v1[3]) };
  *(us4*)(xb + base)     = a;
  *(us4*)(xb + base + 4) = b;
  f32x4 z = {0.f, 0.f, 0.f, 0.f};
  *(f32x4*)(out + base)     = z;
  *(f32x4*)(out + base + 4) = z;
}

// ---- convert all 3 weight tensors f32 -> bf16 (8M elems each) ----
__global__ __launch_bounds__(256) void k_convw(const float* __restrict__ g,
                                               const float* __restrict__ u,
                                               const float* __restrict__ d,
                                               u16* __restrict__ gb,
                                               u16* __restrict__ ub,
                                               u16* __restrict__ db) {
  const long NTH = 3L << 20;   // 24M elems / 8 per thread
  for (long i = (long)blockIdx.x * 256 + threadIdx.x; i < NTH; i += (long)gridDim.x * 256) {
    int which = (int)(i >> 20);
    long off = (i & ((1L << 20) - 1)) * 8;
    const float* src = which == 0 ? g : (which == 1 ? u : d);
    u16* dst = which == 0 ? gb : (which == 1 ? ub : db);
    f32x4 v0 = *(const f32x4*)(src + off);
    f32x4 v1 = *(const f32x4*)(src + off + 4);
    us4 a = { f2bf(v0[0]), f2bf(v0[1]), f2bf(v0[2]), f2bf(v0[3]) };
    us4 b = { f2bf(v1[0]), f2bf(v1[1]), f2bf(v1[2]), f2bf(v1[3]) };
    *(us4*)(dst + off)     = a;
    *(us4*)(dst + off + 4) = b;
  }
}

// ---- routing: counts -> 128-padded segment bases -> permutation ----
__global__ __launch_bounds__(256) void k_route(const int* __restrict__ sel,
                                               int* __restrict__ hdr,   // seg_base[9]
                                               int* __restrict__ perm) {
  __shared__ int cnt[NEXP];
  __shared__ int cur[NEXP];
  int tid = threadIdx.x;
  if (tid < NEXP) cnt[tid] = 0;
  __syncthreads();
  for (int p = tid; p < NPAIR; p += 256) atomicAdd(&cnt[sel[p]], 1);
  __syncthreads();
  if (tid == 0) {
    int acc = 0;
    for (int e = 0; e < NEXP; e++) {
      hdr[e] = acc;
      cur[e] = acc;
      acc += (cnt[e] + 127) & ~127;   // pad each segment to 128
    }
    hdr[NEXP] = acc;
  }
  __syncthreads();
  for (int i = tid; i < PERM_MAX; i += 256) perm[i] = -1;
  __syncthreads();
  for (int p = tid; p < NPAIR; p += 256) {
    int e = sel[p];
    int slot = atomicAdd(&cur[e], 1);
    perm[slot] = p;
  }
}

// ---- GEMM 1: gate + up fused, SwiGLU epilogue -> hbuf (bf16) ----
// BM=128, BN=64, BK=64; 4 waves in 2x2; per-wave 64x32 per matrix (m-rep 4, n-rep 2)
__global__ __launch_bounds__(256) void k_gateup(const u16* __restrict__ xb,
                                                const u16* __restrict__ gwb,
                                                const u16* __restrict__ uwb,
                                                const int* __restrict__ hdr,
                                                const int* __restrict__ perm,
                                                u16* __restrict__ hbuf) {
  __shared__ __align__(16) u16 lA[128 * 64];   // 16 KB
  __shared__ __align__(16) u16 lBg[64 * 64];   //  8 KB
  __shared__ __align__(16) u16 lBu[64 * 64];   //  8 KB

  const int tid = threadIdx.x, lane = tid & 63, wv = tid >> 6;
  const int n0 = blockIdx.x * 64, m0 = blockIdx.y * 128;
  const int total = hdr[NEXP];
  if (m0 >= total) return;
  int e = 0;
  #pragma unroll
  for (int k = 1; k < NEXP; k++) if (m0 >= hdr[k]) e = k;

  // A staging: 16 issues of 1 KiB; 4 per wave. LDS linear; global src inverse-swizzled.
  const u16* srcA[4]; u16* dstA[4];
  #pragma unroll
  for (int j = 0; j < 4; j++) {
    int rt = wv * 32 + j * 8 + (lane >> 3);       // row within tile
    int p = perm[m0 + rt];
    int tok = (p < 0) ? 0 : (p >> 1);
    int sw = (lane & 7) ^ (rt & 7);               // inverse-swizzled 16B slot
    srcA[j] = xb + (size_t)tok * HID + sw * 8;
    dstA[j] = &lA[(wv * 32 + j * 8) * 64];
  }
  // B staging: 8 issues per matrix; 2 per wave each.
  const u16* srcG[2]; const u16* srcU[2]; int dstBo[2];
  const size_t eb = (size_t)e * (1 << 20);
  #pragma unroll
  for (int j = 0; j < 2; j++) {
    int rt = wv * 16 + j * 8 + (lane >> 3);
    int sw = (lane & 7) ^ (rt & 7);
    srcG[j] = gwb + eb + (size_t)(n0 + rt) * HID + sw * 8;
    srcU[j] = uwb + eb + (size_t)(n0 + rt) * HID + sw * 8;
    dstBo[j] = (wv * 16 + j * 8) * 64;
  }

  const int wm = wv >> 1, wn = wv & 1;
  const int fr = lane & 15, fq = lane >> 4;

  f32x4 accg[4][2], accu[4][2];
  #pragma unroll
  for (int a = 0; a < 4; a++)
    #pragma unroll
    for (int b = 0; b < 2; b++) {
      accg[a][b] = (f32x4){0.f, 0.f, 0.f, 0.f};
      accu[a][b] = (f32x4){0.f, 0.f, 0.f, 0.f};
    }

  for (int kk = 0; kk < HID / 64; kk++) {
    const int k0 = kk * 64;
    #pragma unroll
    for (int j = 0; j < 4; j++) gload16(srcA[j] + k0, dstA[j]);
    #pragma unroll
    for (int j = 0; j < 2; j++) {
      gload16(srcG[j] + k0, &lBg[dstBo[j]]);
      gload16(srcU[j] + k0, &lBu[dstBo[j]]);
    }
    __syncthreads();
    #pragma unroll
    for (int kk2 = 0; kk2 < 2; kk2++) {
      bf16x8 af[4], bg[2], bu[2];
      #pragma unroll
      for (int m2 = 0; m2 < 4; m2++) {
        int r = wm * 64 + m2 * 16 + fr, q = kk2 * 4 + fq;
        af[m2] = *(const bf16x8*)&lA[r * 64 + (q ^ (r & 7)) * 8];
      }
      #pragma unroll
      for (int n2 = 0; n2 < 2; n2++) {
        int r = wn * 32 + n2 * 16 + fr, q = kk2 * 4 + fq;
        bg[n2] = *(const bf16x8*)&lBg[r * 64 + (q ^ (r & 7)) * 8];
        bu[n2] = *(const bf16x8*)&lBu[r * 64 + (q ^ (r & 7)) * 8];
      }
      #pragma unroll
      for (int m2 = 0; m2 < 4; m2++)
        #pragma unroll
        for (int n2 = 0; n2 < 2; n2++) {
          accg[m2][n2] = mfma_bf16(af[m2], bg[n2], accg[m2][n2]);
          accu[m2][n2] = mfma_bf16(af[m2], bu[n2], accu[m2][n2]);
        }
    }
    __syncthreads();
  }

  // epilogue: h = silu(g) * u -> bf16
  #pragma unroll
  for (int m2 = 0; m2 < 4; m2++)
    #pragma unroll
    for (int n2 = 0; n2 < 2; n2++)
      #pragma unroll
      for (int q = 0; q < 4; q++) {
        int row = m0 + wm * 64 + m2 * 16 + fq * 4 + q;
        int col = n0 + wn * 32 + n2 * 16 + fr;
        float g = accg[m2][n2][q];
        float u = accu[m2][n2][q];
        float h = (g / (1.0f + __expf(-g))) * u;
        hbuf[(size_t)row * HID + col] = f2bf(h);
      }
}

// ---- GEMM 2: down, weighted atomic scatter into out ----
// BM=128, BN=64, BK=64; same wave decomposition
__global__ __launch_bounds__(256) void k_down(const u16* __restrict__ hbuf,
                                              const u16* __restrict__ dwb,
                                              const int* __restrict__ hdr,
                                              const int* __restrict__ perm,
                                              const float* __restrict__ rw,
                                              float* __restrict__ out) {
  __shared__ __align__(16) u16 lA[128 * 64];   // 16 KB
  __shared__ __align__(16) u16 lB[64 * 64];    //  8 KB

  const int tid = threadIdx.x, lane = tid & 63, wv = tid >> 6;
  const int n0 = blockIdx.x * 64, m0 = blockIdx.y * 128;
  const int total = hdr[NEXP];
  if (m0 >= total) return;
  int e = 0;
  #pragma unroll
  for (int k = 1; k < NEXP; k++) if (m0 >= hdr[k]) e = k;

  const u16* srcA[4]; u16* dstA[4];
  #pragma unroll
  for (int j = 0; j < 4; j++) {
    int rt = wv * 32 + j * 8 + (lane >> 3);
    int sw = (lane & 7) ^ (rt & 7);
    srcA[j] = hbuf + (size_t)(m0 + rt) * HID + sw * 8;
    dstA[j] = &lA[(wv * 32 + j * 8) * 64];
  }
  const u16* srcB[2]; int dstBo[2];
  const size_t eb = (size_t)e * (1 << 20);
  #pragma unroll
  for (int j = 0; j < 2; j++) {
    int rt = wv * 16 + j * 8 + (lane >> 3);
    int sw = (lane & 7) ^ (rt & 7);
    srcB[j] = dwb + eb + (size_t)(n0 + rt) * HID + sw * 8;
    dstBo[j] = (wv * 16 + j * 8) * 64;
  }

  const int wm = wv >> 1, wn = wv & 1;
  const int fr = lane & 15, fq = lane >> 4;

  f32x4 acc[4][2];
  #pragma unroll
  for (int a = 0; a < 4; a++)
    #pragma unroll
    for (int b = 0; b < 2; b++) acc[a][b] = (f32x4){0.f, 0.f, 0.f, 0.f};

  for (int kk = 0; kk < HID / 64; kk++) {
    const int k0 = kk * 64;
    #pragma unroll
    for (int j = 0; j < 4; j++) gload16(srcA[j] + k0, dstA[j]);
    #pragma unroll
    for (int j = 0; j < 2; j++) gload16(srcB[j] + k0, &lB[dstBo[j]]);
    __syncthreads();
    #pragma unroll
    for (int kk2 = 0; kk2 < 2; kk2++) {
      bf16x8 af[4], bf[2];
      #pragma unroll
      for (int m2 = 0; m2 < 4; m2++) {
        int r = wm * 64 + m2 * 16 + fr, q = kk2 * 4 + fq;
        af[m2] = *(const bf16x8*)&lA[r * 64 + (q ^ (r & 7)) * 8];
      }
      #pragma unroll
      for (int n2 = 0; n2 < 2; n2++) {
        int r = wn * 32 + n2 * 16 + fr, q = kk2 * 4 + fq;
        bf[n2] = *(const bf16x8*)&lB[r * 64 + (q ^ (r & 7)) * 8];
      }
      #pragma unroll
      for (int m2 = 0; m2 < 4; m2++)
        #pragma unroll
        for (int n2 = 0; n2 < 2; n2++)
          acc[m2][n2] = mfma_bf16(af[m2], bf[n2], acc[m2][n2]);
    }
    __syncthreads();
  }

  // epilogue: out[token] += w * val
  #pragma unroll
  for (int m2 = 0; m2 < 4; m2++)
    #pragma unroll
    for (int q = 0; q < 4; q++) {
      int row = m0 + wm * 64 + m2 * 16 + fq * 4 + q;
      int p = perm[row];
      if (p < 0) continue;
      int t = p >> 1;
      float w = rw[p];
      #pragma unroll
      for (int n2 = 0; n2 < 2; n2++) {
        int col = n0 + wn * 32 + n2 * 16 + fr;
        atomicAdd(&out[(size_t)t * HID + col], acc[m2][n2][q] * w);
      }
    }
}

extern "C" void kernel_launch(void* const* d_in, const int* in_sizes, int n_in,
                              void* d_out, int out_size, void* d_ws, size_t ws_size,
                              hipStream_t stream) {
  const float* x   = (const float*)d_in[0];
  const float* rw  = (const float*)d_in[1];
  const int*   sel = (const int*)d_in[2];
  const float* gw  = (const float*)d_in[4];
  const float* uw  = (const float*)d_in[5];
  const float* dw  = (const float*)d_in[6];
  float* out = (float*)d_out;

  char* ws = (char*)d_ws;
  int*  hdr  = (int*)ws;                          // seg_base[9]
  int*  perm = (int*)(ws + 1024);                 // PERM_MAX ints
  u16*  xb   = (u16*)(ws + (1 << 16));            // 2M bf16 = 4 MiB
  u16*  gwb  = xb + (2 << 20);                    // 8M bf16 = 16 MiB
  u16*  uwb  = gwb + (8 << 20);                   // 16 MiB
  u16*  dwb  = uwb + (8 << 20);                   // 16 MiB
  u16*  hbuf = dwb + (8 << 20);                   // 5120*1024 bf16 = 10 MiB

  k_prep <<<dim3(1024), dim3(256), 0, stream>>>(x, xb, out);
  k_convw<<<dim3(4096), dim3(256), 0, stream>>>(gw, uw, dw, gwb, uwb, dwb);
  k_route<<<dim3(1),    dim3(256), 0, stream>>>(sel, hdr, perm);
  k_gateup<<<dim3(16, MT_MAX), dim3(256), 0, stream>>>(xb, gwb, uwb, hdr, perm, hbuf);
  k_down  <<<dim3(16, MT_MAX), dim3(256), 0, stream>>>(hbuf, dwb, hdr, perm, rw, out);
}